// Round 1
// baseline (1757.059 us; speedup 1.0000x reference)
//
#include <hip/hip_runtime.h>
#include <math.h>

// BracketNet: out[s] = x_t + ctx, ctx = GELU_exact(W_h · [ctx; x_t] + b_h)
// S=2048, B=64, D=512, H=8, DIM=64. 512 independent chains (b,h), each a
// strict sequential recurrence over S. One 64-lane wave per chain; lane = d.

#define S_LEN 2048
#define B_SZ  64
#define D_SZ  512
#define H_SZ  8
#define DIM   64
#define STRIDE ((size_t)B_SZ * D_SZ)   // floats between consecutive s

__global__ __launch_bounds__(64, 1) void bracket_scan(
    const float* __restrict__ src, const float* __restrict__ W,
    const float* __restrict__ bias, float* __restrict__ out)
{
    const int lane = threadIdx.x;        // output dim d within head
    const int bb   = blockIdx.x >> 3;    // batch index  (0..63)
    const int hh   = blockIdx.x & 7;     // head index   (0..7)

    // Per-lane weight row: W[hh, lane, 0:128] = [Wc(64) | Wx(64)], 128 VGPRs.
    const float4* wrow =
        reinterpret_cast<const float4*>(W + (size_t)(hh * DIM + lane) * (2 * DIM));
    float4 w4[32];
#pragma unroll
    for (int i = 0; i < 32; ++i) w4[i] = wrow[i];

    const float bv = bias[hh * DIM + lane];

    // Ping-pong LDS: [ctx(64) | x_t(64)] per buffer.
    __shared__ float buf[2][2 * DIM];

    const float* sp = src + (size_t)bb * D_SZ + hh * DIM + lane;
    float*       op = out + (size_t)bb * D_SZ + hh * DIM + lane;

    // Prefetch pipeline, depth 3 (x0 = x_s at loop top).
    float x0 = sp[0];
    float x1 = sp[STRIDE];
    float x2 = sp[2 * STRIDE];

    buf[0][lane]       = 0.0f;   // ctx_0 = 0
    buf[0][DIM + lane] = x0;
    __syncthreads();

    const float inv_sqrt2 = 0.70710678118654752440f;

    for (int s = 0; s < S_LEN; ++s) {
        const int cur = s & 1;

        // Prefetch x_{s+3} (hides ~900-cyc HBM latency across ~3 steps).
        float x3 = 0.0f;
        if (s + 3 < S_LEN) x3 = sp[(size_t)(s + 3) * STRIDE];

        // y[d] = b[d] + sum_{k<128} W[d,k] * [ctx; x_t][k]
        const float4* c4 = reinterpret_cast<const float4*>(buf[cur]);
        float a0 = bv, a1 = 0.0f, a2 = 0.0f, a3 = 0.0f;
#pragma unroll
        for (int i = 0; i < 32; ++i) {
            const float4 c = c4[i];
            a0 = fmaf(w4[i].x, c.x, a0);
            a1 = fmaf(w4[i].y, c.y, a1);
            a2 = fmaf(w4[i].z, c.z, a2);
            a3 = fmaf(w4[i].w, c.w, a3);
        }
        const float y = (a0 + a1) + (a2 + a3);

        // exact GELU: 0.5*y*(1+erf(y/sqrt(2)))
        const float g = 0.5f * y * (1.0f + erff(y * inv_sqrt2));

        // r = x_t + new_ctx  (fire-and-forget store)
        op[(size_t)s * STRIDE] = x0 + g;

        // Publish next step's [ctx | x] into the other buffer.
        buf[cur ^ 1][lane]       = g;
        buf[cur ^ 1][DIM + lane] = x1;
        __syncthreads();

        x0 = x1; x1 = x2; x2 = x3;
    }
}

extern "C" void kernel_launch(void* const* d_in, const int* in_sizes, int n_in,
                              void* d_out, int out_size, void* d_ws, size_t ws_size,
                              hipStream_t stream) {
    const float* src = (const float*)d_in[0];
    const float* W   = (const float*)d_in[1];
    const float* b   = (const float*)d_in[2];
    float* out       = (float*)d_out;

    hipLaunchKernelGGL(bracket_scan, dim3(B_SZ * H_SZ), dim3(64), 0, stream,
                       src, W, b, out);
}

// Round 2
// 1520.808 us; speedup vs baseline: 1.1553x; 1.1553x over previous
//
#include <hip/hip_runtime.h>
#include <math.h>

// BracketNet: out[s] = x_t + ctx, ctx = GELU_exact(W_h · [ctx; x_t] + b_h)
// S=2048, B=64, D=512, H=8, DIM=64. 512 independent chains (b,h), each a
// strict sequential recurrence over S. One 64-lane wave per chain; lane = d.
//
// Round-1 lessons:
//  - NO __syncthreads(): single-wave block is lockstep; the barrier forced
//    s_waitcnt vmcnt(0) every step, draining the x-prefetch and store queue
//    (full HBM latency on the critical path each iteration).
//  - Pin W in VGPRs (asm keep-alive): compiler was re-loading all 32 float4
//    weights from global every step (VGPR_Count was only 108).

#define S_LEN 2048
#define B_SZ  64
#define D_SZ  512
#define H_SZ  8
#define DIM   64
#define STRIDE ((size_t)B_SZ * D_SZ)   // floats between consecutive s

__global__ __launch_bounds__(64, 1) void bracket_scan(
    const float* __restrict__ src, const float* __restrict__ W,
    const float* __restrict__ bias, float* __restrict__ out)
{
    const int lane = threadIdx.x;        // output dim d within head
    const int bb   = blockIdx.x >> 3;    // batch index  (0..63)
    const int hh   = blockIdx.x & 7;     // head index   (0..7)

    // Per-lane weight row: W[hh, lane, 0:128] = [Wc(64) | Wx(64)], 128 VGPRs.
    const float4* wrow =
        reinterpret_cast<const float4*>(W + (size_t)(hh * DIM + lane) * (2 * DIM));
    float4 w4[32];
#pragma unroll
    for (int i = 0; i < 32; ++i) w4[i] = wrow[i];
    // Force the whole weight row to be register-resident across the loop;
    // without this the compiler sinks the loads into the loop body.
#pragma unroll
    for (int i = 0; i < 32; ++i)
        asm volatile("" : "+v"(w4[i].x), "+v"(w4[i].y), "+v"(w4[i].z), "+v"(w4[i].w));

    const float bv = bias[hh * DIM + lane];

    // Ping-pong LDS: [ctx(64) | x_t(64)] per buffer. Single wave -> no
    // barrier needed, only lgkmcnt ordering (compiler-inserted).
    __shared__ float buf[2][2 * DIM];

    const float* sp = src + (size_t)bb * D_SZ + hh * DIM + lane;
    float*       op = out + (size_t)bb * D_SZ + hh * DIM + lane;

    // Prefetch pipeline, depth 3 (x0 = x_s at loop top).
    float x0 = sp[0];
    float x1 = sp[STRIDE];
    float x2 = sp[2 * STRIDE];

    buf[0][lane]       = 0.0f;   // ctx_0 = 0
    buf[0][DIM + lane] = x0;

    const float inv_sqrt2 = 0.70710678118654752440f;

    for (int s = 0; s < S_LEN; ++s) {
        const int cur = s & 1;

        // Prefetch x_{s+3}; branchless clamp keeps the load in the pipeline.
        const size_t ps = (s + 3 < S_LEN) ? (size_t)(s + 3) : (size_t)(S_LEN - 1);
        const float x3 = sp[ps * STRIDE];

        // y[d] = b[d] + sum_{k<128} W[d,k] * [ctx; x_t][k]
        const float4* c4 = reinterpret_cast<const float4*>(buf[cur]);
        float a0 = bv, a1 = 0.0f, a2 = 0.0f, a3 = 0.0f;
#pragma unroll
        for (int i = 0; i < 32; ++i) {
            const float4 c = c4[i];
            a0 = fmaf(w4[i].x, c.x, a0);
            a1 = fmaf(w4[i].y, c.y, a1);
            a2 = fmaf(w4[i].z, c.z, a2);
            a3 = fmaf(w4[i].w, c.w, a3);
        }
        const float y = (a0 + a1) + (a2 + a3);

        // exact GELU: 0.5*y*(1+erf(y/sqrt(2)))
        const float g = 0.5f * y * (1.0f + erff(y * inv_sqrt2));

        // r = x_t + new_ctx  (fire-and-forget store, no drain)
        op[(size_t)s * STRIDE] = x0 + g;

        // Publish next step's [ctx | x] into the other buffer.
        buf[cur ^ 1][lane]       = g;
        buf[cur ^ 1][DIM + lane] = x1;

        x0 = x1; x1 = x2; x2 = x3;
    }
}

extern "C" void kernel_launch(void* const* d_in, const int* in_sizes, int n_in,
                              void* d_out, int out_size, void* d_ws, size_t ws_size,
                              hipStream_t stream) {
    const float* src = (const float*)d_in[0];
    const float* W   = (const float*)d_in[1];
    const float* b   = (const float*)d_in[2];
    float* out       = (float*)d_out;

    hipLaunchKernelGGL(bracket_scan, dim3(B_SZ * H_SZ), dim3(64), 0, stream,
                       src, W, b, out);
}

// Round 3
// 1427.622 us; speedup vs baseline: 1.2308x; 1.0653x over previous
//
#include <hip/hip_runtime.h>
#include <math.h>

// BracketNet: out[s] = x_t + ctx, ctx = GELU_exact(W_h · [ctx; x_t] + b_h)
// S=2048, B=64, D=512, H=8, DIM=64. 512 independent sequential chains (b,h);
// one 64-lane wave per chain, lane = output dim d. Latency-bound on the
// per-step critical path: g -> ds_write -> ds_read(broadcast) -> 64 ctx-FMAs
// -> gelu -> g. The x-half of the dot and all global traffic are off-path.
//
// Round-2 lesson: "+v" keep-alive asm does NOT pin loaded values — the
// compiler rematerializes readonly loads inside the loop (VGPR_Count stayed
// 100). Fix: load W via asm volatile global_load_dwordx4; volatile asm
// outputs cannot be re-executed, forcing true register residency.

typedef float f32x4 __attribute__((ext_vector_type(4)));

#define S_LEN 2048
#define B_SZ  64
#define D_SZ  512
#define DIM   64
#define STRIDE ((size_t)(B_SZ * D_SZ))   // floats between consecutive s

__global__ __launch_bounds__(64, 1) void bracket_scan(
    const float* __restrict__ src, const float* __restrict__ W,
    const float* __restrict__ bias, float* __restrict__ out)
{
    const int lane = threadIdx.x;        // output dim d within head
    const int bb   = blockIdx.x >> 3;    // batch index  (0..63)
    const int hh   = blockIdx.x & 7;     // head index   (0..7)

    // ---- W row -> VGPRs via volatile asm loads (non-rematerializable).
    // w[0..15] = ctx weights (k=0..63), w[16..31] = x weights (k=64..127).
    f32x4 w[32];
    {
        const float* wb = W + (size_t)(hh * DIM + lane) * (2 * DIM);
#pragma unroll
        for (int i = 0; i < 32; ++i)
            asm volatile("global_load_dwordx4 %0, %1, off offset:%2"
                         : "=v"(w[i]) : "v"(wb), "i"(16 * i));
    }
    asm volatile("s_waitcnt vmcnt(0)" ::: "memory");
    __builtin_amdgcn_sched_barrier(0);   // nothing crosses the wait

    const float bv = bias[hh * DIM + lane];

    __shared__ float cbuf[2][DIM];   // ctx ping-pong (the serial path)
    __shared__ float xbuf[4][DIM];   // x broadcast ring, written 4 steps ahead

    const float* sp = src + (size_t)bb * D_SZ + hh * DIM + lane;
    float*       op = out + (size_t)bb * D_SZ + hh * DIM + lane;

    // Per-lane residual pipeline: xr0..xr3 = x[s..s+3] at loop top.
    float xr0 = sp[0];
    float xr1 = sp[STRIDE];
    float xr2 = sp[2 * STRIDE];
    float xr3 = sp[3 * STRIDE];

    cbuf[0][lane] = 0.0f;            // ctx_0 = 0
    xbuf[0][lane] = xr0;
    xbuf[1][lane] = xr1;
    xbuf[2][lane] = xr2;
    xbuf[3][lane] = xr3;

    const float* pp    = sp + 4 * STRIDE;                  // x[s+4]
    const float* plast = sp + (size_t)(S_LEN - 1) * STRIDE;

    const float is2 = 0.70710678118654752440f;

    // One recurrence step: reads cbuf[rb], writes cbuf[rb^1]; consumes
    // residual xres; prefetches x[s+4] into ring slot (s+4)&3 (== s&3) and
    // returns it for the register shift.
    auto half = [&](int s, int rb, float xres) -> float {
        // residual prefetch (fire-and-forget; clamped, stays in pipeline)
        float xn = *pp;
        pp = (pp < plast) ? (pp + STRIDE) : plast;

        const f32x4* xv = (const f32x4*)xbuf[s & 3];   // written 4 steps ago
        const f32x4* cv = (const f32x4*)cbuf[rb];      // written last step

        float a0 = bv, a1 = 0.f, a2 = 0.f, a3 = 0.f;
        float a4 = 0.f, a5 = 0.f, a6 = 0.f, a7 = 0.f;

        // x-half first: independent of the ctx round-trip, hides its latency.
#pragma unroll
        for (int i = 0; i < 16; i += 2) {
            f32x4 u0 = xv[i], u1 = xv[i + 1];
            a0 = fmaf(w[16 + i].x, u0.x, a0);
            a1 = fmaf(w[16 + i].y, u0.y, a1);
            a2 = fmaf(w[16 + i].z, u0.z, a2);
            a3 = fmaf(w[16 + i].w, u0.w, a3);
            a4 = fmaf(w[17 + i].x, u1.x, a4);
            a5 = fmaf(w[17 + i].y, u1.y, a5);
            a6 = fmaf(w[17 + i].z, u1.z, a6);
            a7 = fmaf(w[17 + i].w, u1.w, a7);
        }
        // ctx-half: the true serial dependency.
#pragma unroll
        for (int i = 0; i < 16; i += 2) {
            f32x4 c0 = cv[i], c1 = cv[i + 1];
            a0 = fmaf(w[i].x, c0.x, a0);
            a1 = fmaf(w[i].y, c0.y, a1);
            a2 = fmaf(w[i].z, c0.z, a2);
            a3 = fmaf(w[i].w, c0.w, a3);
            a4 = fmaf(w[i + 1].x, c1.x, a4);
            a5 = fmaf(w[i + 1].y, c1.y, a5);
            a6 = fmaf(w[i + 1].z, c1.z, a6);
            a7 = fmaf(w[i + 1].w, c1.w, a7);
        }
        const float y = ((a0 + a1) + (a2 + a3)) + ((a4 + a5) + (a6 + a7));

        // exact GELU
        const float g = 0.5f * y * (1.0f + erff(y * is2));

        *op = xres + g;                 // fire-and-forget store
        op += STRIDE;

        cbuf[rb ^ 1][lane] = g;         // publish ctx for next step
        xbuf[s & 3][lane]  = xn;        // slot (s+4)&3 == s&3
        return xn;
    };

    for (int s = 0; s < S_LEN; s += 2) {
        float xn0 = half(s, 0, xr0);
        xr0 = xr1; xr1 = xr2; xr2 = xr3; xr3 = xn0;
        float xn1 = half(s + 1, 1, xr0);
        xr0 = xr1; xr1 = xr2; xr2 = xr3; xr3 = xn1;
    }
}

extern "C" void kernel_launch(void* const* d_in, const int* in_sizes, int n_in,
                              void* d_out, int out_size, void* d_ws, size_t ws_size,
                              hipStream_t stream) {
    const float* src = (const float*)d_in[0];
    const float* W   = (const float*)d_in[1];
    const float* b   = (const float*)d_in[2];
    float* out       = (float*)d_out;

    hipLaunchKernelGGL(bracket_scan, dim3(B_SZ * 8), dim3(64), 0, stream,
                       src, W, b, out);
}